// Round 1
// baseline (913.822 us; speedup 1.0000x reference)
//
#include <hip/hip_runtime.h>

#define B_DIM 4096
#define D_DIM 512
#define H_DIM 16
#define HD_DIM 8192

#define BM 128
#define BN 128
#define BK 16

__global__ __launch_bounds__(256) void prep_kernel(const float* __restrict__ conf,
                                                   float* __restrict__ lam,
                                                   float* __restrict__ count) {
  int i = blockIdx.x * 256 + threadIdx.x;
  float l = 1.0f - conf[i];
  l = fminf(fmaxf(l, 0.0f), 1.0f);
  float m = (l > 0.3f) ? 1.0f : 0.0f;
  lam[i] = l * m;
  for (int off = 32; off > 0; off >>= 1) m += __shfl_down(m, off, 64);
  __shared__ float wsum[4];
  int lane = threadIdx.x & 63;
  int w = threadIdx.x >> 6;
  if (lane == 0) wsum[w] = m;
  __syncthreads();
  if (threadIdx.x == 0) atomicAdd(count, wsum[0] + wsum[1] + wsum[2] + wsum[3]);
}

// Generic f32 GEMM: C(M,N) = A(M,K) @ B(K,N)
// AT=false: A row-major-ish (sa_k==1).  AT=true: A "transposed" (sa_m==1).
// B always has sb_n==1 (row stride ldb).
// mode 0: atomicAdd(C, acc*alpha)   (split-K accumulation; C pre-zeroed)
// mode 1: C = acc*alpha             (plain store)
// mode 2: C = addsrc + acc * 1/(count+1e-6)
// batched: grid.z = batch index (strides sa_b/sb_b/sc_b/sadd_b); else grid.z = split-K slice.
template <bool AT>
__global__ __launch_bounds__(256) void gemm_k(
    const float* __restrict__ A, long long sa_m, long long sa_k, long long sa_b,
    const float* __restrict__ Bp, long long ldb, long long sb_b,
    float* __restrict__ C, long long ldc, long long sc_b,
    const float* __restrict__ addsrc, long long sadd_b,
    const float* __restrict__ rowscale,
    const float* __restrict__ count_ptr,
    float alpha, int K, int k_chunk, int batched, int mode) {
  __shared__ float As[BK][BM];
  __shared__ float Bs[BK][BN];

  const int tid = threadIdx.x;
  const int n0 = blockIdx.x * BN;
  const int m0 = blockIdx.y * BM;
  const int bz = blockIdx.z;

  const float* Ab = A;
  const float* Bb = Bp;
  float* Cb = C;
  const float* addb = addsrc;
  long long k0;
  int Kl;
  if (batched) {
    Ab += (long long)bz * sa_b;
    Bb += (long long)bz * sb_b;
    Cb += (long long)bz * sc_b;
    if (addsrc) addb += (long long)bz * sadd_b;
    k0 = 0;
    Kl = K;
  } else {
    k0 = (long long)bz * k_chunk;
    Kl = k_chunk;
  }

  float acc[8][8];
#pragma unroll
  for (int r = 0; r < 8; ++r)
#pragma unroll
    for (int c = 0; c < 8; ++c) acc[r][c] = 0.0f;

  const int tx = tid & 15;
  const int ty = tid >> 4;

  for (int t = 0; t < Kl; t += BK) {
    if (AT) {
      // A contiguous along m: load float4 along m, store straight into k-major LDS.
#pragma unroll
      for (int p = 0; p < 2; ++p) {
        int k = (tid >> 5) + p * 8;
        int mq = (tid & 31) << 2;
        const float* src = Ab + (k0 + t + k) * sa_k + (m0 + mq);
        float4 v = *(const float4*)src;
        *(float4*)&As[k][mq] = v;
      }
    } else {
      // A contiguous along k: load float4 along k, transpose via 4 scalar LDS writes.
#pragma unroll
      for (int p = 0; p < 2; ++p) {
        int m = (tid >> 2) + p * 64;
        int kq = (tid & 3) << 2;
        const float* src = Ab + (long long)(m0 + m) * sa_m + (k0 + t + kq);
        float4 v = *(const float4*)src;
        As[kq + 0][m] = v.x;
        As[kq + 1][m] = v.y;
        As[kq + 2][m] = v.z;
        As[kq + 3][m] = v.w;
      }
    }
#pragma unroll
    for (int p = 0; p < 2; ++p) {
      int k = (tid >> 5) + p * 8;
      int nq = (tid & 31) << 2;
      const float* src = Bb + (k0 + t + k) * ldb + (n0 + nq);
      float4 v = *(const float4*)src;
      if (rowscale) {
        float s = rowscale[k0 + t + k];
        v.x *= s;
        v.y *= s;
        v.z *= s;
        v.w *= s;
      }
      *(float4*)&Bs[k][nq] = v;
    }
    __syncthreads();
#pragma unroll
    for (int kk = 0; kk < BK; ++kk) {
      float a[8], b[8];
      *(float4*)&a[0] = *(const float4*)&As[kk][ty * 8];
      *(float4*)&a[4] = *(const float4*)&As[kk][ty * 8 + 4];
      *(float4*)&b[0] = *(const float4*)&Bs[kk][tx * 8];
      *(float4*)&b[4] = *(const float4*)&Bs[kk][tx * 8 + 4];
#pragma unroll
      for (int r = 0; r < 8; ++r)
#pragma unroll
        for (int c = 0; c < 8; ++c) acc[r][c] = fmaf(a[r], b[c], acc[r][c]);
    }
    __syncthreads();
  }

  if (mode == 0) {
#pragma unroll
    for (int r = 0; r < 8; ++r) {
      long long row = m0 + ty * 8 + r;
#pragma unroll
      for (int c = 0; c < 8; ++c) {
        atomicAdd(&Cb[row * ldc + (n0 + tx * 8 + c)], acc[r][c] * alpha);
      }
    }
  } else if (mode == 1) {
#pragma unroll
    for (int r = 0; r < 8; ++r) {
      long long row = m0 + ty * 8 + r;
      float4 v0 = make_float4(acc[r][0] * alpha, acc[r][1] * alpha, acc[r][2] * alpha,
                              acc[r][3] * alpha);
      float4 v1 = make_float4(acc[r][4] * alpha, acc[r][5] * alpha, acc[r][6] * alpha,
                              acc[r][7] * alpha);
      *(float4*)&Cb[row * ldc + n0 + tx * 8] = v0;
      *(float4*)&Cb[row * ldc + n0 + tx * 8 + 4] = v1;
    }
  } else {
    float inv = 1.0f / (*count_ptr + 1e-6f);
#pragma unroll
    for (int r = 0; r < 8; ++r) {
      long long row = m0 + ty * 8 + r;
      const float4 a0 = *(const float4*)&addb[row * ldc + n0 + tx * 8];
      const float4 a1 = *(const float4*)&addb[row * ldc + n0 + tx * 8 + 4];
      float4 v0 = make_float4(a0.x + acc[r][0] * inv, a0.y + acc[r][1] * inv,
                              a0.z + acc[r][2] * inv, a0.w + acc[r][3] * inv);
      float4 v1 = make_float4(a1.x + acc[r][4] * inv, a1.y + acc[r][5] * inv,
                              a1.z + acc[r][6] * inv, a1.w + acc[r][7] * inv);
      *(float4*)&Cb[row * ldc + n0 + tx * 8] = v0;
      *(float4*)&Cb[row * ldc + n0 + tx * 8 + 4] = v1;
    }
  }
}

extern "C" void kernel_launch(void* const* d_in, const int* in_sizes, int n_in,
                              void* d_out, int out_size, void* d_ws, size_t ws_size,
                              hipStream_t stream) {
  (void)in_sizes; (void)n_in; (void)out_size; (void)ws_size;
  const float* zq   = (const float*)d_in[0];
  const float* zs   = (const float*)d_in[1];
  const float* zv   = (const float*)d_in[2];
  const float* conf = (const float*)d_in[3];
  const float* Wk   = (const float*)d_in[4];
  const float* Wv   = (const float*)d_in[5];
  const float* Wo   = (const float*)d_in[6];
  const float* mem  = (const float*)d_in[7];

  float* vret = (float*)d_out;                         // (B, D)
  float* newmem = vret + (long long)B_DIM * D_DIM;     // (H, D, D)

  float* ws = (float*)d_ws;
  float* count = ws;            // 1 float
  float* lam = ws + 64;         // 4096 floats
  float* P = ws + 8192;         // 512*512
  float* Q = P + 262144;        // 512*512
  float* S = Q + 262144;        // 512*512
  float* U = S + 262144;        // 16*512*512

  // Zero count, (lam region harmlessly), P, Q, S for atomic split-K accumulation.
  hipMemsetAsync(d_ws, 0, (size_t)(8192 + 3 * 262144) * sizeof(float), stream);

  // lam_m and mask count
  prep_kernel<<<B_DIM / 256, 256, 0, stream>>>(conf, lam, count);

  // P = Wk(512x8192) @ Mflat(8192x512), split-K 8x1024
  gemm_k<false><<<dim3(4, 4, 8), 256, 0, stream>>>(
      Wk, 8192, 1, 0, mem, 512, 0, P, 512, 0,
      nullptr, 0, nullptr, nullptr, 1.0f, 8192, 1024, 0, 0);

  // Q = P @ Wo, split-K 4x128
  gemm_k<false><<<dim3(4, 4, 4), 256, 0, stream>>>(
      P, 512, 1, 0, Wo, 512, 0, Q, 512, 0,
      nullptr, 0, nullptr, nullptr, 1.0f, 512, 128, 0, 0);

  // v_ret = (1/16) * zq(4096x512) @ Q(512x512)
  gemm_k<false><<<dim3(4, 32, 1), 256, 0, stream>>>(
      zq, 512, 1, 0, Q, 512, 0, vret, 512, 0,
      nullptr, 0, nullptr, nullptr, 1.0f / 16.0f, 512, 512, 0, 1);

  // S = zs^T(512x4096) @ diag(lam) @ zv(4096x512), split-K 8x512
  gemm_k<true><<<dim3(4, 4, 8), 256, 0, stream>>>(
      zs, 1, 512, 0, zv, 512, 0, S, 512, 0,
      nullptr, 0, lam, nullptr, 1.0f, 4096, 512, 0, 0);

  // U_h = S @ Wv_h  (batched over 16 heads)
  gemm_k<false><<<dim3(4, 4, 16), 256, 0, stream>>>(
      S, 512, 1, 0, Wv, 8192, 512, U, 512, 262144,
      nullptr, 0, nullptr, nullptr, 1.0f, 512, 512, 1, 1);

  // new_memory_h = mem_h + (Wk_h^T @ U_h) * 1/(count+1e-6)  (batched over 16 heads)
  gemm_k<true><<<dim3(4, 4, 16), 256, 0, stream>>>(
      Wk, 1, 8192, 512, U, 512, 262144, newmem, 512, 262144,
      mem, 262144, nullptr, count, 1.0f, 512, 512, 1, 2);
}

// Round 2
// 252.964 us; speedup vs baseline: 3.6125x; 3.6125x over previous
//
#include <hip/hip_runtime.h>

typedef unsigned short u16;
typedef __attribute__((ext_vector_type(8))) short bf16x8;
typedef __attribute__((ext_vector_type(4))) float f32x4;

#define B_DIM 4096
#define D_DIM 512
#define H_DIM 16

__device__ __forceinline__ u16 f2bf(float f) {
  union { float f; unsigned u; } x;
  x.f = f;
  unsigned r = x.u + 0x7FFFu + ((x.u >> 16) & 1u);
  return (u16)(r >> 16);
}

__global__ __launch_bounds__(256) void prep_kernel(const float* __restrict__ conf,
                                                   float* __restrict__ lam,
                                                   float* __restrict__ count) {
  int i = blockIdx.x * 256 + threadIdx.x;
  float l = 1.0f - conf[i];
  l = fminf(fmaxf(l, 0.0f), 1.0f);
  float m = (l > 0.3f) ? 1.0f : 0.0f;
  lam[i] = l * m;
  for (int off = 32; off > 0; off >>= 1) m += __shfl_down(m, off, 64);
  __shared__ float wsum[4];
  int lane = threadIdx.x & 63;
  int w = threadIdx.x >> 6;
  if (lane == 0) wsum[w] = m;
  __syncthreads();
  if (threadIdx.x == 0) atomicAdd(count, wsum[0] + wsum[1] + wsum[2] + wsum[3]);
}

// out[(c)(rows) + r] = in[r*cols + c] * (scale ? scale[r] : 1), f32 -> bf16
__global__ __launch_bounds__(256) void transpose_cvt(const float* __restrict__ in,
                                                     u16* __restrict__ out,
                                                     int rows, int cols,
                                                     const float* __restrict__ scale) {
  __shared__ float tile[32][33];
  int tx = threadIdx.x & 31, ty = threadIdx.x >> 5;
  long long c0 = (long long)blockIdx.x * 32, r0 = (long long)blockIdx.y * 32;
#pragma unroll
  for (int i = 0; i < 4; ++i) {
    int row = ty + i * 8;
    float v = in[(r0 + row) * cols + c0 + tx];
    if (scale) v *= scale[r0 + row];
    tile[row][tx] = v;
  }
  __syncthreads();
#pragma unroll
  for (int i = 0; i < 4; ++i) {
    int orow = ty + i * 8;
    out[(c0 + orow) * rows + r0 + tx] = f2bf(tile[tx][orow]);
  }
}

// plain f32 -> bf16, 4 elems/thread, exact-size grids
__global__ __launch_bounds__(256) void convert_bf(const float* __restrict__ in,
                                                  u16* __restrict__ out) {
  long long i = ((long long)blockIdx.x * 256 + threadIdx.x) * 4;
  float4 v = *(const float4*)&in[i];
  ushort4 o;
  o.x = f2bf(v.x); o.y = f2bf(v.y); o.z = f2bf(v.z); o.w = f2bf(v.w);
  *(ushort4*)&out[i] = o;
}

// C(M,N) = alpha * A(M,K) @ Bt(N,K)^T  -- both operands bf16 row-major, k contiguous.
// mode 0: atomicAdd into f32 C (split-K; C pre-zeroed)
// mode 1: store bf16
// mode 2: store f32 * alpha
// mode 3: store f32 = addsrc + acc / (count + 1e-6)
// batched: grid.z = batch (strides sa_b/sb_b/sc_b/sadd_b); else grid.z = split-K slice.
#define LDT 72  // 64 + 8 bf16 pad (16B) -> only free 2-way bank aliasing on ds_read_b128
__global__ __launch_bounds__(256) void gemm_bt(
    const u16* __restrict__ A, long long lda, long long sa_b,
    const u16* __restrict__ Bt, long long ldb, long long sb_b,
    void* __restrict__ Cv, long long ldc, long long sc_b,
    const float* __restrict__ addsrc, long long sadd_b,
    const float* __restrict__ count_ptr,
    float alpha, int K, int k_chunk, int batched, int mode) {
  __shared__ u16 As[64 * LDT];
  __shared__ u16 Bs[64 * LDT];

  const int tid = threadIdx.x;
  const long long n0 = (long long)blockIdx.x * 64;
  const long long m0 = (long long)blockIdx.y * 64;
  const int bz = blockIdx.z;

  const u16* Ab = A;
  const u16* Bb = Bt;
  long long coff = 0;
  long long k0 = 0;
  int Kl = K;
  if (batched) {
    Ab += (long long)bz * sa_b;
    Bb += (long long)bz * sb_b;
    coff = (long long)bz * sc_b;
  } else {
    k0 = (long long)bz * k_chunk;
    Kl = k_chunk;
  }

  const int lr = tid >> 3;         // 0..31 tile row
  const int lc = (tid & 7) * 8;    // k offset, 8 bf16 = 16B
  const int lane = tid & 63;
  const int wave = tid >> 6;
  const int wm = (wave & 1) * 32;
  const int wn = (wave >> 1) * 32;
  const int fm = lane & 15;
  const int fg = lane >> 4;

  f32x4 zero = {0.f, 0.f, 0.f, 0.f};
  f32x4 acc[2][2];
  acc[0][0] = zero; acc[0][1] = zero; acc[1][0] = zero; acc[1][1] = zero;

  for (int t = 0; t < Kl; t += 64) {
#pragma unroll
    for (int p = 0; p < 2; ++p) {
      int row = lr + p * 32;
      uint4 av = *(const uint4*)(Ab + (m0 + row) * lda + k0 + t + lc);
      uint4 bv = *(const uint4*)(Bb + (n0 + row) * ldb + k0 + t + lc);
      *(uint4*)&As[row * LDT + lc] = av;
      *(uint4*)&Bs[row * LDT + lc] = bv;
    }
    __syncthreads();
#pragma unroll
    for (int kc = 0; kc < 64; kc += 32) {
      bf16x8 a0 = *(const bf16x8*)&As[(wm + fm) * LDT + kc + fg * 8];
      bf16x8 a1 = *(const bf16x8*)&As[(wm + 16 + fm) * LDT + kc + fg * 8];
      bf16x8 b0 = *(const bf16x8*)&Bs[(wn + fm) * LDT + kc + fg * 8];
      bf16x8 b1 = *(const bf16x8*)&Bs[(wn + 16 + fm) * LDT + kc + fg * 8];
      acc[0][0] = __builtin_amdgcn_mfma_f32_16x16x32_bf16(a0, b0, acc[0][0], 0, 0, 0);
      acc[0][1] = __builtin_amdgcn_mfma_f32_16x16x32_bf16(a0, b1, acc[0][1], 0, 0, 0);
      acc[1][0] = __builtin_amdgcn_mfma_f32_16x16x32_bf16(a1, b0, acc[1][0], 0, 0, 0);
      acc[1][1] = __builtin_amdgcn_mfma_f32_16x16x32_bf16(a1, b1, acc[1][1], 0, 0, 0);
    }
    __syncthreads();
  }

  float inv = 0.0f;
  if (mode == 3) inv = 1.0f / (*count_ptr + 1e-6f);
  const float* addb = addsrc ? (addsrc + (batched ? (long long)bz * sadd_b : 0)) : (const float*)0;

#pragma unroll
  for (int mi = 0; mi < 2; ++mi) {
#pragma unroll
    for (int r = 0; r < 4; ++r) {
      long long row = m0 + wm + mi * 16 + fg * 4 + r;
#pragma unroll
      for (int ni = 0; ni < 2; ++ni) {
        long long col = n0 + wn + ni * 16 + fm;
        long long hidx = row * ldc + col;
        float v = acc[mi][ni][r] * alpha;
        if (mode == 0) {
          atomicAdd((float*)Cv + coff + hidx, v);
        } else if (mode == 1) {
          ((u16*)Cv)[coff + hidx] = f2bf(v);
        } else if (mode == 2) {
          ((float*)Cv)[coff + hidx] = v;
        } else {
          ((float*)Cv)[coff + hidx] = addb[hidx] + acc[mi][ni][r] * inv;
        }
      }
    }
  }
}

extern "C" void kernel_launch(void* const* d_in, const int* in_sizes, int n_in,
                              void* d_out, int out_size, void* d_ws, size_t ws_size,
                              hipStream_t stream) {
  (void)in_sizes; (void)n_in; (void)out_size; (void)ws_size;
  const float* zq   = (const float*)d_in[0];
  const float* zs   = (const float*)d_in[1];
  const float* zv   = (const float*)d_in[2];
  const float* conf = (const float*)d_in[3];
  const float* Wk   = (const float*)d_in[4];
  const float* Wv   = (const float*)d_in[5];
  const float* Wo   = (const float*)d_in[6];
  const float* mem  = (const float*)d_in[7];

  float* vret = (float*)d_out;                      // (B, D)
  float* newmem = vret + (long long)B_DIM * D_DIM;  // (H, D, D)

  // workspace layout
  float* count = (float*)d_ws;                                // @0
  float* Pf    = (float*)((char*)d_ws + 256);                 // 1 MB f32
  float* Sf    = (float*)((char*)d_ws + 256 + 1048576);       // 1 MB f32
  float* lam   = (float*)((char*)d_ws + 2097408);             // 16 KB
  u16* bb      = (u16*)((char*)d_ws + 2113792);
  u16* zsT   = bb;               // 512 x 4096
  u16* zvlT  = bb + 2097152;     // 512 x 4096 (lam-scaled)
  u16* zq_bf = bb + 4194304;     // 4096 x 512
  u16* Wk_bf = bb + 6291456;     // 512 x 8192
  u16* WkT   = bb + 10485760;    // 8192 x 512  (= per-head Wk_h^T)
  u16* WvT   = bb + 14680064;    // 8192 x 512
  u16* memT  = bb + 18874368;    // 512 x 8192
  u16* WoT   = bb + 23068672;    // 512 x 512
  u16* P_bf  = bb + 23330816;    // 512 x 512
  u16* QT    = bb + 23592960;    // 512 x 512  (= Q^T)
  u16* S_bf  = bb + 23855104;    // 512 x 512
  u16* UT    = bb + 24117248;    // 16 x 512 x 512 (= U_h^T)

  // zero count + Pf + Sf (split-K atomic targets)
  hipMemsetAsync(d_ws, 0, 2097408, stream);

  prep_kernel<<<B_DIM / 256, 256, 0, stream>>>(conf, lam, count);

  // transposes + converts (all f32 -> bf16)
  transpose_cvt<<<dim3(16, 128), 256, 0, stream>>>(zs, zsT, 4096, 512, nullptr);
  transpose_cvt<<<dim3(16, 128), 256, 0, stream>>>(zv, zvlT, 4096, 512, lam);
  transpose_cvt<<<dim3(256, 16), 256, 0, stream>>>(Wk, WkT, 512, 8192, nullptr);
  transpose_cvt<<<dim3(256, 16), 256, 0, stream>>>(Wv, WvT, 512, 8192, nullptr);
  transpose_cvt<<<dim3(16, 16), 256, 0, stream>>>(Wo, WoT, 512, 512, nullptr);
  transpose_cvt<<<dim3(16, 256), 256, 0, stream>>>(mem, memT, 8192, 512, nullptr);
  convert_bf<<<2048, 256, 0, stream>>>(zq, zq_bf);
  convert_bf<<<4096, 256, 0, stream>>>(Wk, Wk_bf);

  // G1: P(512x512) = Wk(512x8192) @ Mflat  (Bt = memT), split-K 8, f32 atomics
  gemm_bt<<<dim3(8, 8, 8), 256, 0, stream>>>(
      Wk_bf, 8192, 0, memT, 8192, 0, Pf, 512, 0,
      nullptr, 0, nullptr, 1.0f, 8192, 1024, 0, 0);
  convert_bf<<<256, 256, 0, stream>>>(Pf, P_bf);

  // G2: QT = Wo^T-row-major as A, Bt = P  ->  QT[m][n] = Q[n][m]
  gemm_bt<<<dim3(8, 8, 1), 256, 0, stream>>>(
      WoT, 512, 0, P_bf, 512, 0, QT, 512, 0,
      nullptr, 0, nullptr, 1.0f, 512, 512, 0, 1);

  // G3: vret = (1/16) * zq @ Q   (Bt = QT), f32 out
  gemm_bt<<<dim3(8, 64, 1), 256, 0, stream>>>(
      zq_bf, 512, 0, QT, 512, 0, vret, 512, 0,
      nullptr, 0, nullptr, 1.0f / 16.0f, 512, 512, 0, 2);

  // G4: S = zs^T @ diag(lam) @ zv  (A = zsT, Bt = zvlT), split-K 4, f32 atomics
  gemm_bt<<<dim3(8, 8, 4), 256, 0, stream>>>(
      zsT, 4096, 0, zvlT, 4096, 0, Sf, 512, 0,
      nullptr, 0, nullptr, 1.0f, 4096, 1024, 0, 0);
  convert_bf<<<256, 256, 0, stream>>>(Sf, S_bf);

  // G5: UT_h = (S @ Wv_h)^T  (A = WvT_h, Bt = S), batched over 16 heads
  gemm_bt<<<dim3(8, 8, 16), 256, 0, stream>>>(
      WvT, 512, 262144, S_bf, 512, 0, UT, 512, 262144,
      nullptr, 0, nullptr, 1.0f, 512, 512, 1, 1);

  // G6: newmem_h = mem_h + (Wk_h^T @ U_h) / (count+1e-6)  (A = WkT_h, Bt = UT_h)
  gemm_bt<<<dim3(8, 8, 16), 256, 0, stream>>>(
      WkT, 512, 262144, UT, 512, 262144, newmem, 512, 262144,
      mem, 262144, count, 1.0f, 512, 512, 1, 3);
}